// Round 7
// baseline (437.569 us; speedup 1.0000x reference)
//
#include <hip/hip_runtime.h>

#define EPS 1e-5f

typedef int int32x4 __attribute__((ext_vector_type(4)));

typedef const __attribute__((address_space(1))) unsigned int* gaddr_t;
typedef __attribute__((address_space(3))) unsigned int* laddr_t;

// ===========================================================================
// Kernel 1: partial |w| sums. 256 fat blocks x 256 thr x 64 float4 each.
// fp64 accumulate, deterministic two-stage.
// ===========================================================================
__global__ __launch_bounds__(256) void k_abssum(const float* __restrict__ w,
                                                double* __restrict__ partials) {
    int t = threadIdx.x;
    const float4* wv = (const float4*)w + (size_t)blockIdx.x * 16384;
    double s = 0.0;
#pragma unroll 8
    for (int i = 0; i < 64; ++i) {
        float4 v = wv[i * 256 + t];
        s += (double)(fabsf(v.x) + fabsf(v.y) + fabsf(v.z) + fabsf(v.w));
    }
    for (int off = 32; off; off >>= 1) s += __shfl_down(s, off);
    __shared__ double sm[4];
    int lane = t & 63, wid = t >> 6;
    if (lane == 0) sm[wid] = s;
    __syncthreads();
    if (t == 0) partials[blockIdx.x] = sm[0] + sm[1] + sm[2] + sm[3];
}

// Kernel 2: reduce 256 partials -> delta = mean(|w|) + EPS
__global__ __launch_bounds__(256) void k_delta(const double* __restrict__ partials,
                                               float* __restrict__ delta) {
    int t = threadIdx.x;
    double s = partials[t];
    for (int off = 32; off; off >>= 1) s += __shfl_down(s, off);
    __shared__ double sm[4];
    int lane = t & 63, wid = t >> 6;
    if (lane == 0) sm[wid] = s;
    __syncthreads();
    if (t == 0) {
        double mean = (sm[0] + sm[1] + sm[2] + sm[3]) / 16777216.0;
        *delta = (float)mean + EPS;
    }
}

// ===========================================================================
// Kernel 3: ternary weight quant. 512 fat blocks x 256 thr x 32 float4.
// ===========================================================================
__global__ __launch_bounds__(256) void k_wquant(const float* __restrict__ w,
                                                const float* __restrict__ deltap,
                                                signed char* __restrict__ tq) {
    float rd = 1.0f / (*deltap);
    int t = threadIdx.x;
    size_t b4 = (size_t)blockIdx.x * 8192;  // float4 index base
    const float4* wv = (const float4*)w;
    int* qo = (int*)tq;
#pragma unroll 8
    for (int i = 0; i < 32; ++i) {
        float4 v = wv[b4 + i * 256 + t];
        float a[4] = {v.x, v.y, v.z, v.w};
        int packed = 0;
#pragma unroll
        for (int j = 0; j < 4; ++j) {
            float r = rintf(a[j] * rd);
            r = fminf(1.0f, fmaxf(-1.0f, r));
            packed |= ((int)r & 0xff) << (8 * j);
        }
        qo[b4 + i * 256 + t] = packed;
    }
}

// ===========================================================================
// Kernel 4: activation quant. ONE WAVE PER ROW (no block barrier, no LDS).
// 2048 blocks x 4 waves; wave handles row blockIdx.x*4 + waveid.
// Row = 1024 float4; 64 lanes x 16 float4 held in registers.
// ===========================================================================
__global__ __launch_bounds__(256) void k_xquant(const float* __restrict__ x,
                                                signed char* __restrict__ q) {
    int t = threadIdx.x;
    int lane = t & 63, wid = t >> 6;
    size_t row = (size_t)blockIdx.x * 4 + wid;
    const float4* xv = (const float4*)(x + row * 4096);
    float4 v[16];
    float m = 0.0f;
#pragma unroll
    for (int i = 0; i < 16; ++i) {
        v[i] = xv[i * 64 + lane];
        m = fmaxf(m, fmaxf(fmaxf(fabsf(v[i].x), fabsf(v[i].y)),
                           fmaxf(fabsf(v[i].z), fabsf(v[i].w))));
    }
#pragma unroll
    for (int off = 32; off; off >>= 1) m = fmaxf(m, __shfl_xor(m, off));
    float inv = 127.0f / (m + EPS);
    int* qo = (int*)(q + row * 4096);
#pragma unroll
    for (int i = 0; i < 16; ++i) {
        float a[4] = {v[i].x, v[i].y, v[i].z, v[i].w};
        int packed = 0;
#pragma unroll
        for (int j = 0; j < 4; ++j) {
            float r = rintf(a[j] * inv);
            r = fminf(127.0f, fmaxf(-128.0f, r));
            packed |= ((int)r & 0xff) << (8 * j);
        }
        qo[i * 64 + lane] = packed;
    }
}

// ===========================================================================
// Kernel 5: int8 GEMM  C[m][n] = (delta/127) * sum_k q[m][k]*t[n][k]
// M=8192 N=4096 K=4096. m97 structure: 128x128 tile, 4 waves 2x2, BK=64,
// mfma_i32_16x16x64_i8, global_load_lds width-16 staging, linear LDS.
// NEW: bijective XCD-aware block swizzle (2048 wgs, 2048%8==0).
// ===========================================================================
__global__ __launch_bounds__(256) void k_gemm(const signed char* __restrict__ A,
                                              const signed char* __restrict__ B,
                                              const float* __restrict__ deltap,
                                              float* __restrict__ C) {
    __shared__ alignas(16) signed char As[8192];  // [128 rows][64 k-bytes]
    __shared__ alignas(16) signed char Bs[8192];  // [128 rows][64 k-bytes]

    int t = threadIdx.x;
    int lane = t & 63, wid = t >> 6;
    int wr = wid >> 1, wc = wid & 1;

    // XCD swizzle: orig id o -> wg = (o%8)*256 + o/8 (bijective on [0,2048))
    int o = blockIdx.y * 32 + blockIdx.x;
    int wg = (o & 7) * 256 + (o >> 3);
    int bx = wg & 31;   // N-tile
    int by = wg >> 5;   // M-tile

    size_t brow = (size_t)by * 128;
    size_t bcol = (size_t)bx * 128;

    int32x4 acc[4][4];
#pragma unroll
    for (int i = 0; i < 4; ++i)
#pragma unroll
        for (int j = 0; j < 4; ++j) acc[i][j] = (int32x4)(0);

    const signed char* ga = A + (brow + (size_t)(wid * 16 + (lane >> 2))) * 4096 + (lane & 3) * 16;
    const signed char* gb = B + (bcol + (size_t)(wid * 16 + (lane >> 2))) * 4096 + (lane & 3) * 16;
    signed char* lA = As + wid * 1024;
    signed char* lB = Bs + wid * 1024;

    int fa_off = (wr * 64 + (lane & 15)) * 64 + (lane >> 4) * 16;
    int fb_off = (wc * 64 + (lane & 15)) * 64 + (lane >> 4) * 16;

    for (int kt = 0; kt < 64; ++kt) {
        int koff = kt * 64;
        __builtin_amdgcn_global_load_lds((gaddr_t)(ga + koff), (laddr_t)lA, 16, 0, 0);
        __builtin_amdgcn_global_load_lds((gaddr_t)(ga + koff + (size_t)64 * 4096),
                                         (laddr_t)(lA + 4096), 16, 0, 0);
        __builtin_amdgcn_global_load_lds((gaddr_t)(gb + koff), (laddr_t)lB, 16, 0, 0);
        __builtin_amdgcn_global_load_lds((gaddr_t)(gb + koff + (size_t)64 * 4096),
                                         (laddr_t)(lB + 4096), 16, 0, 0);
        __syncthreads();

        int32x4 af[4], bf[4];
#pragma unroll
        for (int i = 0; i < 4; ++i)
            af[i] = *(const int32x4*)(As + fa_off + i * 16 * 64);
#pragma unroll
        for (int j = 0; j < 4; ++j)
            bf[j] = *(const int32x4*)(Bs + fb_off + j * 16 * 64);

#pragma unroll
        for (int i = 0; i < 4; ++i)
#pragma unroll
            for (int j = 0; j < 4; ++j)
                acc[i][j] = __builtin_amdgcn_mfma_i32_16x16x64_i8(af[i], bf[j], acc[i][j], 0, 0, 0);
        __syncthreads();
    }

    float scale = (*deltap) / 127.0f;
    size_t orow0 = brow + wr * 64 + (lane >> 4) * 4;
    size_t ocol0 = bcol + wc * 64 + (lane & 15);
#pragma unroll
    for (int i = 0; i < 4; ++i)
#pragma unroll
        for (int j = 0; j < 4; ++j) {
#pragma unroll
            for (int r = 0; r < 4; ++r) {
                C[(orow0 + i * 16 + r) * 4096 + ocol0 + j * 16] =
                    scale * (float)acc[i][j][r];
            }
        }
}

// ===========================================================================
// FALLBACK PATH (small ws): needs only ~45 KB of scratch.
// ===========================================================================

__global__ __launch_bounds__(256) void k_gamma(const float* __restrict__ x,
                                               float* __restrict__ gamma) {
    int t = threadIdx.x;
    int lane = t & 63, wid = t >> 6;
    size_t row = (size_t)blockIdx.x * 4 + wid;
    const float4* xv = (const float4*)(x + row * 4096);
    float m = 0.0f;
#pragma unroll
    for (int i = 0; i < 16; ++i) {
        float4 v = xv[i * 64 + lane];
        m = fmaxf(m, fmaxf(fmaxf(fabsf(v.x), fabsf(v.y)),
                           fmaxf(fabsf(v.z), fabsf(v.w))));
    }
#pragma unroll
    for (int off = 32; off; off >>= 1) m = fmaxf(m, __shfl_xor(m, off));
    if (lane == 0) gamma[row] = m + EPS;
}

// fp32 tiled GEMM, 64x64 tile, BK=32, on-the-fly quantization of both operands.
__global__ __launch_bounds__(256) void k_gemm_fb(const float* __restrict__ x,
                                                 const float* __restrict__ w,
                                                 const float* __restrict__ deltap,
                                                 const float* __restrict__ gamma,
                                                 float* __restrict__ C) {
    __shared__ float As[64][33];
    __shared__ float Bs[64][33];
    int t = threadIdx.x;
    int tx = t & 15, ty = t >> 4;
    size_t brow = (size_t)blockIdx.y * 64;
    size_t bcol = (size_t)blockIdx.x * 64;
    float delta = *deltap;
    float rd = 1.0f / delta;
    int lr = t >> 3;
    int lc = (t & 7) * 4;
    float inv0 = 127.0f / gamma[brow + lr];
    float inv1 = 127.0f / gamma[brow + lr + 32];
    float acc[4][4] = {{0.0f}};

    for (int kt = 0; kt < 128; ++kt) {
        int k0 = kt * 32;
#pragma unroll
        for (int h = 0; h < 2; ++h) {
            int row = lr + h * 32;
            float inv = h ? inv1 : inv0;
            float4 v = *(const float4*)(x + (brow + row) * 4096 + k0 + lc);
            As[row][lc + 0] = fminf(127.f, fmaxf(-128.f, rintf(v.x * inv))) * (1.0f / 127.0f);
            As[row][lc + 1] = fminf(127.f, fmaxf(-128.f, rintf(v.y * inv))) * (1.0f / 127.0f);
            As[row][lc + 2] = fminf(127.f, fmaxf(-128.f, rintf(v.z * inv))) * (1.0f / 127.0f);
            As[row][lc + 3] = fminf(127.f, fmaxf(-128.f, rintf(v.w * inv))) * (1.0f / 127.0f);
            float4 u = *(const float4*)(w + (bcol + row) * 4096 + k0 + lc);
            Bs[row][lc + 0] = fminf(1.f, fmaxf(-1.f, rintf(u.x * rd))) * delta;
            Bs[row][lc + 1] = fminf(1.f, fmaxf(-1.f, rintf(u.y * rd))) * delta;
            Bs[row][lc + 2] = fminf(1.f, fmaxf(-1.f, rintf(u.z * rd))) * delta;
            Bs[row][lc + 3] = fminf(1.f, fmaxf(-1.f, rintf(u.w * rd))) * delta;
        }
        __syncthreads();
#pragma unroll 8
        for (int k = 0; k < 32; ++k) {
            float a[4], b[4];
#pragma unroll
            for (int i = 0; i < 4; ++i) { a[i] = As[ty * 4 + i][k]; b[i] = Bs[tx * 4 + i][k]; }
#pragma unroll
            for (int i = 0; i < 4; ++i)
#pragma unroll
                for (int j = 0; j < 4; ++j) acc[i][j] += a[i] * b[j];
        }
        __syncthreads();
    }
#pragma unroll
    for (int i = 0; i < 4; ++i)
#pragma unroll
        for (int j = 0; j < 4; ++j)
            C[(brow + ty * 4 + i) * 4096 + (bcol + tx * 4 + j)] = acc[i][j];
}

// ===========================================================================
extern "C" void kernel_launch(void* const* d_in, const int* in_sizes, int n_in,
                              void* d_out, int out_size, void* d_ws, size_t ws_size,
                              hipStream_t stream) {
    const float* x = (const float*)d_in[0];   // (4,2048,4096) fp32
    const float* w = (const float*)d_in[1];   // (4096,4096) fp32
    float* out = (float*)d_out;               // (4,2048,4096) fp32
    char* ws = (char*)d_ws;

    const size_t FULL_WS = 50339848;  // q(32M) + tq(16M) + partials(2K) + delta
    const size_t FB_WS   = 45056;     // partials(2K) + delta + gamma(32K)

    if (ws_size >= FULL_WS) {
        signed char* q  = (signed char*)ws;                 // 33,554,432 B
        signed char* tq = (signed char*)(ws + 33554432);    // 16,777,216 B
        double* partials = (double*)(ws + 50331648);        // 2,048 B used
        float* delta = (float*)(ws + 50339840);             // 4 B

        k_abssum<<<256, 256, 0, stream>>>(w, partials);
        k_delta<<<1, 256, 0, stream>>>(partials, delta);
        k_wquant<<<512, 256, 0, stream>>>(w, delta, tq);
        k_xquant<<<2048, 256, 0, stream>>>(x, q);
        dim3 grid(32, 64);  // N/128, M/128
        k_gemm<<<grid, 256, 0, stream>>>(q, tq, delta, out);
    } else if (ws_size >= FB_WS) {
        double* partials = (double*)ws;                     // 2,048 B used
        float* delta = (float*)(ws + 8192);                 // 4 B
        float* gamma = (float*)(ws + 12288);                // 32,768 B

        k_abssum<<<256, 256, 0, stream>>>(w, partials);
        k_delta<<<1, 256, 0, stream>>>(partials, delta);
        k_gamma<<<2048, 256, 0, stream>>>(x, gamma);
        dim3 grid(64, 128);  // N/64, M/64
        k_gemm_fb<<<grid, 256, 0, stream>>>(x, w, delta, gamma, out);
    }
}

// Round 9
// 426.064 us; speedup vs baseline: 1.0270x; 1.0270x over previous
//
#include <hip/hip_runtime.h>

#define EPS 1e-5f

typedef int int32x4 __attribute__((ext_vector_type(4)));

typedef const __attribute__((address_space(1))) unsigned int* gaddr_t;
typedef __attribute__((address_space(3))) unsigned int* laddr_t;

// ===========================================================================
// Kernel 1 (merged): blocks [0,2048): activation quant, one wave per row.
//                    blocks [2048,2304): partial |w| sums (fp64, two-stage).
// The two jobs are independent (xquant doesn't need delta); merging saves a
// launch and lets the dispatcher fill the machine with both.
// ===========================================================================
__global__ __launch_bounds__(256) void k_xabs(const float* __restrict__ x,
                                              const float* __restrict__ w,
                                              signed char* __restrict__ q,
                                              double* __restrict__ partials) {
    int t = threadIdx.x;
    if (blockIdx.x < 2048) {
        // ---- activation quant: row = blockIdx.x*4 + waveid, 1024 float4/row
        int lane = t & 63, wid = t >> 6;
        size_t row = (size_t)blockIdx.x * 4 + wid;
        const float4* xv = (const float4*)(x + row * 4096);
        float4 v[16];
        float m = 0.0f;
#pragma unroll
        for (int i = 0; i < 16; ++i) {
            v[i] = xv[i * 64 + lane];
            m = fmaxf(m, fmaxf(fmaxf(fabsf(v[i].x), fabsf(v[i].y)),
                               fmaxf(fabsf(v[i].z), fabsf(v[i].w))));
        }
#pragma unroll
        for (int off = 32; off; off >>= 1) m = fmaxf(m, __shfl_xor(m, off));
        float inv = 127.0f / (m + EPS);
        int* qo = (int*)(q + row * 4096);
#pragma unroll
        for (int i = 0; i < 16; ++i) {
            float a[4] = {v[i].x, v[i].y, v[i].z, v[i].w};
            int packed = 0;
#pragma unroll
            for (int j = 0; j < 4; ++j) {
                float r = rintf(a[j] * inv);
                r = fminf(127.0f, fmaxf(-128.0f, r));
                packed |= ((int)r & 0xff) << (8 * j);
            }
            qo[i * 64 + lane] = packed;
        }
    } else {
        // ---- |w| partial sums: 256 blocks x 256 thr x 64 float4
        int b = blockIdx.x - 2048;
        const float4* wv = (const float4*)w + (size_t)b * 16384;
        double s = 0.0;
#pragma unroll 8
        for (int i = 0; i < 64; ++i) {
            float4 v = wv[i * 256 + t];
            s += (double)(fabsf(v.x) + fabsf(v.y) + fabsf(v.z) + fabsf(v.w));
        }
        for (int off = 32; off; off >>= 1) s += __shfl_down(s, off);
        __shared__ double sm[4];
        int lane = t & 63, wid = t >> 6;
        if (lane == 0) sm[wid] = s;
        __syncthreads();
        if (t == 0) partials[b] = sm[0] + sm[1] + sm[2] + sm[3];
    }
}

// Kernel 2: reduce 256 partials -> delta = mean(|w|) + EPS
__global__ __launch_bounds__(256) void k_delta(const double* __restrict__ partials,
                                               float* __restrict__ delta) {
    int t = threadIdx.x;
    double s = partials[t];
    for (int off = 32; off; off >>= 1) s += __shfl_down(s, off);
    __shared__ double sm[4];
    int lane = t & 63, wid = t >> 6;
    if (lane == 0) sm[wid] = s;
    __syncthreads();
    if (t == 0) {
        double mean = (sm[0] + sm[1] + sm[2] + sm[3]) / 16777216.0;
        *delta = (float)mean + EPS;
    }
}

// ===========================================================================
// Kernel 3: ternary weight quant. 512 fat blocks x 256 thr x 32 float4.
// ===========================================================================
__global__ __launch_bounds__(256) void k_wquant(const float* __restrict__ w,
                                                const float* __restrict__ deltap,
                                                signed char* __restrict__ tq) {
    float rd = 1.0f / (*deltap);
    int t = threadIdx.x;
    size_t b4 = (size_t)blockIdx.x * 8192;  // float4 index base
    const float4* wv = (const float4*)w;
    int* qo = (int*)tq;
#pragma unroll 8
    for (int i = 0; i < 32; ++i) {
        float4 v = wv[b4 + i * 256 + t];
        float a[4] = {v.x, v.y, v.z, v.w};
        int packed = 0;
#pragma unroll
        for (int j = 0; j < 4; ++j) {
            float r = rintf(a[j] * rd);
            r = fminf(1.0f, fmaxf(-1.0f, r));
            packed |= ((int)r & 0xff) << (8 * j);
        }
        qo[b4 + i * 256 + t] = packed;
    }
}

// ===========================================================================
// Kernel 4: int8 GEMM  C[m][n] = (delta/127) * sum_k q[m][k]*t[n][k]
// M=8192 N=4096 K=4096. m97 structure: 128x128 tile, 4 waves 2x2, BK=64,
// mfma_i32_16x16x64_i8, global_load_lds width-16 staging, linear LDS.
// Swizzle REVERTED (r7: chunked XCD swizzle raised FETCH 156->214MB, +7us).
// ===========================================================================
__global__ __launch_bounds__(256) void k_gemm(const signed char* __restrict__ A,
                                              const signed char* __restrict__ B,
                                              const float* __restrict__ deltap,
                                              float* __restrict__ C) {
    __shared__ alignas(16) signed char As[8192];  // [128 rows][64 k-bytes]
    __shared__ alignas(16) signed char Bs[8192];  // [128 rows][64 k-bytes]

    int t = threadIdx.x;
    int lane = t & 63, wid = t >> 6;
    int wr = wid >> 1, wc = wid & 1;

    size_t brow = (size_t)blockIdx.y * 128;
    size_t bcol = (size_t)blockIdx.x * 128;

    int32x4 acc[4][4];
#pragma unroll
    for (int i = 0; i < 4; ++i)
#pragma unroll
        for (int j = 0; j < 4; ++j) acc[i][j] = (int32x4)(0);

    const signed char* ga = A + (brow + (size_t)(wid * 16 + (lane >> 2))) * 4096 + (lane & 3) * 16;
    const signed char* gb = B + (bcol + (size_t)(wid * 16 + (lane >> 2))) * 4096 + (lane & 3) * 16;
    signed char* lA = As + wid * 1024;
    signed char* lB = Bs + wid * 1024;

    int fa_off = (wr * 64 + (lane & 15)) * 64 + (lane >> 4) * 16;
    int fb_off = (wc * 64 + (lane & 15)) * 64 + (lane >> 4) * 16;

    for (int kt = 0; kt < 64; ++kt) {
        int koff = kt * 64;
        __builtin_amdgcn_global_load_lds((gaddr_t)(ga + koff), (laddr_t)lA, 16, 0, 0);
        __builtin_amdgcn_global_load_lds((gaddr_t)(ga + koff + (size_t)64 * 4096),
                                         (laddr_t)(lA + 4096), 16, 0, 0);
        __builtin_amdgcn_global_load_lds((gaddr_t)(gb + koff), (laddr_t)lB, 16, 0, 0);
        __builtin_amdgcn_global_load_lds((gaddr_t)(gb + koff + (size_t)64 * 4096),
                                         (laddr_t)(lB + 4096), 16, 0, 0);
        __syncthreads();

        int32x4 af[4], bf[4];
#pragma unroll
        for (int i = 0; i < 4; ++i)
            af[i] = *(const int32x4*)(As + fa_off + i * 16 * 64);
#pragma unroll
        for (int j = 0; j < 4; ++j)
            bf[j] = *(const int32x4*)(Bs + fb_off + j * 16 * 64);

#pragma unroll
        for (int i = 0; i < 4; ++i)
#pragma unroll
            for (int j = 0; j < 4; ++j)
                acc[i][j] = __builtin_amdgcn_mfma_i32_16x16x64_i8(af[i], bf[j], acc[i][j], 0, 0, 0);
        __syncthreads();
    }

    float scale = (*deltap) / 127.0f;
    size_t orow0 = brow + wr * 64 + (lane >> 4) * 4;
    size_t ocol0 = bcol + wc * 64 + (lane & 15);
#pragma unroll
    for (int i = 0; i < 4; ++i)
#pragma unroll
        for (int j = 0; j < 4; ++j) {
#pragma unroll
            for (int r = 0; r < 4; ++r) {
                C[(orow0 + i * 16 + r) * 4096 + ocol0 + j * 16] =
                    scale * (float)acc[i][j][r];
            }
        }
}

// ===========================================================================
// FALLBACK PATH (small ws): needs only ~45 KB of scratch.
// ===========================================================================

__global__ __launch_bounds__(256) void k_gamma(const float* __restrict__ x,
                                               float* __restrict__ gamma) {
    int t = threadIdx.x;
    int lane = t & 63, wid = t >> 6;
    size_t row = (size_t)blockIdx.x * 4 + wid;
    const float4* xv = (const float4*)(x + row * 4096);
    float m = 0.0f;
#pragma unroll
    for (int i = 0; i < 16; ++i) {
        float4 v = xv[i * 64 + lane];
        m = fmaxf(m, fmaxf(fmaxf(fabsf(v.x), fabsf(v.y)),
                           fmaxf(fabsf(v.z), fabsf(v.w))));
    }
#pragma unroll
    for (int off = 32; off; off >>= 1) m = fmaxf(m, __shfl_xor(m, off));
    if (lane == 0) gamma[row] = m + EPS;
}

__global__ __launch_bounds__(256) void k_abssum_fb(const float* __restrict__ w,
                                                   double* __restrict__ partials) {
    int t = threadIdx.x;
    const float4* wv = (const float4*)w + (size_t)blockIdx.x * 16384;
    double s = 0.0;
#pragma unroll 8
    for (int i = 0; i < 64; ++i) {
        float4 v = wv[i * 256 + t];
        s += (double)(fabsf(v.x) + fabsf(v.y) + fabsf(v.z) + fabsf(v.w));
    }
    for (int off = 32; off; off >>= 1) s += __shfl_down(s, off);
    __shared__ double sm[4];
    int lane = t & 63, wid = t >> 6;
    if (lane == 0) sm[wid] = s;
    __syncthreads();
    if (t == 0) partials[blockIdx.x] = sm[0] + sm[1] + sm[2] + sm[3];
}

// fp32 tiled GEMM, 64x64 tile, BK=32, on-the-fly quantization of both operands.
__global__ __launch_bounds__(256) void k_gemm_fb(const float* __restrict__ x,
                                                 const float* __restrict__ w,
                                                 const float* __restrict__ deltap,
                                                 const float* __restrict__ gamma,
                                                 float* __restrict__ C) {
    __shared__ float As[64][33];
    __shared__ float Bs[64][33];
    int t = threadIdx.x;
    int tx = t & 15, ty = t >> 4;
    size_t brow = (size_t)blockIdx.y * 64;
    size_t bcol = (size_t)blockIdx.x * 64;
    float delta = *deltap;
    float rd = 1.0f / delta;
    int lr = t >> 3;
    int lc = (t & 7) * 4;
    float inv0 = 127.0f / gamma[brow + lr];
    float inv1 = 127.0f / gamma[brow + lr + 32];
    float acc[4][4] = {{0.0f}};

    for (int kt = 0; kt < 128; ++kt) {
        int k0 = kt * 32;
#pragma unroll
        for (int h = 0; h < 2; ++h) {
            int row = lr + h * 32;
            float inv = h ? inv1 : inv0;
            float4 v = *(const float4*)(x + (brow + row) * 4096 + k0 + lc);
            As[row][lc + 0] = fminf(127.f, fmaxf(-128.f, rintf(v.x * inv))) * (1.0f / 127.0f);
            As[row][lc + 1] = fminf(127.f, fmaxf(-128.f, rintf(v.y * inv))) * (1.0f / 127.0f);
            As[row][lc + 2] = fminf(127.f, fmaxf(-128.f, rintf(v.z * inv))) * (1.0f / 127.0f);
            As[row][lc + 3] = fminf(127.f, fmaxf(-128.f, rintf(v.w * inv))) * (1.0f / 127.0f);
            float4 u = *(const float4*)(w + (bcol + row) * 4096 + k0 + lc);
            Bs[row][lc + 0] = fminf(1.f, fmaxf(-1.f, rintf(u.x * rd))) * delta;
            Bs[row][lc + 1] = fminf(1.f, fmaxf(-1.f, rintf(u.y * rd))) * delta;
            Bs[row][lc + 2] = fminf(1.f, fmaxf(-1.f, rintf(u.z * rd))) * delta;
            Bs[row][lc + 3] = fminf(1.f, fmaxf(-1.f, rintf(u.w * rd))) * delta;
        }
        __syncthreads();
#pragma unroll 8
        for (int k = 0; k < 32; ++k) {
            float a[4], b[4];
#pragma unroll
            for (int i = 0; i < 4; ++i) { a[i] = As[ty * 4 + i][k]; b[i] = Bs[tx * 4 + i][k]; }
#pragma unroll
            for (int i = 0; i < 4; ++i)
#pragma unroll
                for (int j = 0; j < 4; ++j) acc[i][j] += a[i] * b[j];
        }
        __syncthreads();
    }
#pragma unroll
    for (int i = 0; i < 4; ++i)
#pragma unroll
        for (int j = 0; j < 4; ++j)
            C[(brow + ty * 4 + i) * 4096 + (bcol + tx * 4 + j)] = acc[i][j];
}

// ===========================================================================
extern "C" void kernel_launch(void* const* d_in, const int* in_sizes, int n_in,
                              void* d_out, int out_size, void* d_ws, size_t ws_size,
                              hipStream_t stream) {
    const float* x = (const float*)d_in[0];   // (4,2048,4096) fp32
    const float* w = (const float*)d_in[1];   // (4096,4096) fp32
    float* out = (float*)d_out;               // (4,2048,4096) fp32
    char* ws = (char*)d_ws;

    const size_t FULL_WS = 50339848;  // q(32M) + tq(16M) + partials(2K) + delta
    const size_t FB_WS   = 45056;     // partials(2K) + delta + gamma(32K)

    if (ws_size >= FULL_WS) {
        signed char* q  = (signed char*)ws;                 // 33,554,432 B
        signed char* tq = (signed char*)(ws + 33554432);    // 16,777,216 B
        double* partials = (double*)(ws + 50331648);        // 2,048 B used
        float* delta = (float*)(ws + 50339840);             // 4 B

        k_xabs<<<2304, 256, 0, stream>>>(x, w, q, partials);   // xquant + |w| partials
        k_delta<<<1, 256, 0, stream>>>(partials, delta);
        k_wquant<<<512, 256, 0, stream>>>(w, delta, tq);
        dim3 grid(32, 64);  // N/128, M/128
        k_gemm<<<grid, 256, 0, stream>>>(q, tq, delta, out);
    } else if (ws_size >= FB_WS) {
        double* partials = (double*)ws;                     // 2,048 B used
        float* delta = (float*)(ws + 8192);                 // 4 B
        float* gamma = (float*)(ws + 12288);                // 32,768 B

        k_abssum_fb<<<256, 256, 0, stream>>>(w, partials);
        k_delta<<<1, 256, 0, stream>>>(partials, delta);
        k_gamma<<<2048, 256, 0, stream>>>(x, gamma);
        dim3 grid(64, 128);  // N/64, M/64
        k_gemm_fb<<<grid, 256, 0, stream>>>(x, w, delta, gamma, out);
    }
}